// Round 1
// baseline (120.125 us; speedup 1.0000x reference)
//
#include <hip/hip_runtime.h>
#include <hip/hip_bf16.h>

#define BB 256
#define NGT 8
#define HWA 10647
#define NC 3
#define EPSF 1e-6f
#define FP16_EPS 0.0009765625f

__device__ __forceinline__ float sigmoid_clip(float x) {
    float s = 1.f / (1.f + expf(-x));
    return fminf(fmaxf(s, EPSF), 1.f - EPSF);
}

__global__ __launch_bounds__(256) void yolo_loss_batch(
    const float* __restrict__ pconf, const float* __restrict__ pcls,
    const float* __restrict__ ptxywh, const float* __restrict__ gboxes,
    const int* __restrict__ glabels, float* __restrict__ partial)
{
    const int b = blockIdx.x;
    const int tid = threadIdx.x;

    __shared__ float lz[HWA];                 // 42588 B
    __shared__ int   s_idx[NGT];
    __shared__ float s_row[NGT][13];
    __shared__ unsigned long long red[4];
    __shared__ int   s_cand[3 * NGT];
    __shared__ int   s_conf[3 * NGT];
    __shared__ int   s_src[3 * NGT];
    __shared__ int   s_ncand;
    __shared__ int   s_npos;
    __shared__ float s_negsum;

    // ---- Phase A: per-GT matching (threads 0..7) ----
    if (tid < NGT) {
        const int i = tid;
        const float* gb = gboxes + ((size_t)b * NGT + i) * 4;
        const float l = gb[0], t = gb[1], r = gb[2], bo = gb[3];
        const float cx = (l + r) * 0.5f, cy = (t + bo) * 0.5f;
        const float w = r - l, h = bo - t;
        const float area_g = w * h;
        const float AW[9] = {0.0276f, 0.0386f, 0.0795f, 0.0721f, 0.1495f, 0.1421f, 0.2788f, 0.375f, 0.897f};
        const float AH[9] = {0.0361f, 0.0697f, 0.0553f, 0.1466f, 0.1087f, 0.2861f, 0.2163f, 0.476f, 0.784f};
        float best = -1.f, baw = AW[0], bah = AH[0];
        int id = 0;
#pragma unroll
        for (int a = 0; a < 9; ++a) {
            float inter = fminf(w, AW[a]) * fminf(h, AH[a]);
            float iou = inter / (area_g + AW[a] * AH[a] - inter);
            if (iou > best) { best = iou; id = a; baw = AW[a]; bah = AH[a]; }
        }
        const int ceng = id / 3, anc = id % 3;
        const int grid = (ceng == 0) ? 52 : ((ceng == 1) ? 26 : 13);
        const int coff = (ceng == 0) ? 0 : ((ceng == 1) ? 8112 : 10140);
        const float gf = (float)grid;
        const int col = (int)(cx * gf);
        const int row = (int)(cy * gf);
        s_idx[i] = coff + (row * grid + col) * 3 + anc;
        float* rr = s_row[i];
        const int lab = glabels[b * NGT + i] - 1;
        rr[0] = 1.f;
        rr[1] = (lab == 0) ? 1.f : 0.f;
        rr[2] = (lab == 1) ? 1.f : 0.f;
        rr[3] = (lab == 2) ? 1.f : 0.f;
        rr[4] = (cx - (float)col / gf) * gf;
        rr[5] = (cy - (float)row / gf) * gf;
        rr[6] = logf(w / baw);
        rr[7] = logf(h / bah);
        rr[8] = 2.f - area_g;
        rr[9] = l; rr[10] = t; rr[11] = r; rr[12] = bo;
    }
    __syncthreads();

    // ---- Phase A2: sequential replay of scatter semantics (thread 0) ----
    if (tid == 0) {
        int ncand = 0;
        for (int i = 0; i < NGT; ++i)
            for (int d = 0; d < 3; ++d) {
                int p = s_idx[i] + d;
                if (p >= HWA) continue;          // OOB scatter is dropped in JAX
                bool seen = false;
                for (int j = 0; j < ncand; ++j) if (s_cand[j] == p) { seen = true; break; }
                if (!seen) s_cand[ncand++] = p;
            }
        int npos = 0;
        for (int c = 0; c < ncand; ++c) {
            const int p = s_cand[c];
            int conf = 0, src = -1;
            for (int i = 0; i < NGT; ++i) {
                const int di = p - s_idx[i];
                if (di >= 0 && di < 3) conf = -1;  // ignore-mark (col 0 only)
                if (di == 0) { conf = 1; src = i; } // full-row set (after mark)
            }
            s_conf[c] = conf; s_src[c] = src;
            if (conf == 1) npos++;
        }
        s_ncand = ncand; s_npos = npos; s_negsum = 0.f;
    }
    __syncthreads();

    // ---- Phase B: lv (g=0) over all HWA positions into LDS ----
    const float* pc = pconf + (size_t)b * HWA;
    for (int p = tid; p < HWA; p += 256) {
        const float ps = sigmoid_clip(pc[p]);
        lz[p] = -log1pf(-ps);
    }
    __syncthreads();
    if (tid == 0) {
        for (int c = 0; c < s_ncand; ++c) lz[s_cand[c]] = 0.f;  // mask pos|ign
    }
    __syncthreads();

    // ---- Phase C: iterative top-k extraction (k = ceil(3*nums_pos)) ----
    const float nums_pos = fmaxf((float)s_npos, FP16_EPS);
    const int k = (int)ceilf(nums_pos * 3.f);
    for (int it = 0; it < k; ++it) {
        float bv = -2.f; int bi = 0;
        for (int p = tid; p < HWA; p += 256) {
            const float v = lz[p];
            if (v > bv) { bv = v; bi = p; }
        }
        // pack: value (positive, monotone bits) | (HWA - idx)  → max-key == max val, tie → min idx
        unsigned long long key =
            ((unsigned long long)__float_as_uint(bv + 2.f) << 32) | (unsigned)(HWA - bi);
#pragma unroll
        for (int off = 32; off > 0; off >>= 1) {
            unsigned long long o = __shfl_down(key, off, 64);
            if (o > key) key = o;
        }
        if ((tid & 63) == 0) red[tid >> 6] = key;
        __syncthreads();
        if (tid == 0) {
            unsigned long long kk = red[0];
            for (int wv = 1; wv < 4; ++wv) if (red[wv] > kk) kk = red[wv];
            const int p = HWA - (int)(kk & 0xffffffffu);
            s_negsum += lz[p];
            lz[p] = -1.f;
        }
        __syncthreads();
    }

    // ---- Phase D: positive-position terms (thread 0, ≤8 positions) ----
    if (tid == 0) {
        float l_cls = 0.f, l_conf_pos = 0.f, l_txty = 0.f, l_twth = 0.f;
        for (int c = 0; c < s_ncand; ++c) {
            if (s_conf[c] != 1) continue;
            const int p = s_cand[c];
            const float* rr = s_row[s_src[c]];
            // conf (g=1): -log(p)
            l_conf_pos += -logf(sigmoid_clip(pc[p]));
            // cls
            const float* pcl = pcls + ((size_t)b * HWA + p) * 3;
#pragma unroll
            for (int cc = 0; cc < 3; ++cc) {
                const float sc = sigmoid_clip(pcl[cc]);
                const float g = rr[1 + cc];
                l_cls += -(g * logf(sc) + (1.f - g) * log1pf(-sc));
            }
            // txty / twth
            const float* pt = ptxywh + ((size_t)b * HWA + p) * 4;
            const float wgt = rr[8];
            float acc = 0.f;
#pragma unroll
            for (int cc = 0; cc < 2; ++cc) {
                const float st = sigmoid_clip(pt[cc]);
                const float g = rr[4 + cc];
                acc += -(g * logf(st) + (1.f - g) * log1pf(-st));
            }
            l_txty += acc * wgt;
            const float d0 = pt[2] - rr[6], d1 = pt[3] - rr[7];
            l_twth += (d0 * d0 + d1 * d1) * wgt;
        }
        partial[b] = (l_conf_pos + s_negsum + l_cls + l_txty + l_twth) / nums_pos;
    }
}

__global__ __launch_bounds__(256) void yolo_loss_reduce(
    const float* __restrict__ partial, float* __restrict__ out)
{
    const int tid = threadIdx.x;
    float v = partial[tid];
#pragma unroll
    for (int off = 32; off > 0; off >>= 1) v += __shfl_down(v, off, 64);
    __shared__ float s[4];
    if ((tid & 63) == 0) s[tid >> 6] = v;
    __syncthreads();
    if (tid == 0) out[0] = (s[0] + s[1] + s[2] + s[3]) * (1.f / (float)BB);
}

extern "C" void kernel_launch(void* const* d_in, const int* in_sizes, int n_in,
                              void* d_out, int out_size, void* d_ws, size_t ws_size,
                              hipStream_t stream) {
    const float* pconf  = (const float*)d_in[0];
    const float* pcls   = (const float*)d_in[1];
    const float* ptxywh = (const float*)d_in[2];
    const float* gboxes = (const float*)d_in[3];
    const int*   glabels = (const int*)d_in[4];
    float* out = (float*)d_out;
    float* partial = (float*)d_ws;

    yolo_loss_batch<<<BB, 256, 0, stream>>>(pconf, pcls, ptxywh, gboxes, glabels, partial);
    yolo_loss_reduce<<<1, 256, 0, stream>>>(partial, out);
}

// Round 2
// 84.688 us; speedup vs baseline: 1.4184x; 1.4184x over previous
//
#include <hip/hip_runtime.h>
#include <hip/hip_bf16.h>

#define BB 256
#define NGT 8
#define HWA 10647
#define NTH 1024
#define CAP 1536
#define EPSF 1e-6f
#define FP16_EPS 0.0009765625f

__device__ __forceinline__ float sigmoid_clip(float x) {
    float s = 1.f / (1.f + expf(-x));
    return fminf(fmaxf(s, EPSF), 1.f - EPSF);
}

__global__ __launch_bounds__(NTH) void yolo_loss_batch(
    const float* __restrict__ pconf, const float* __restrict__ pcls,
    const float* __restrict__ ptxywh, const float* __restrict__ gboxes,
    const int* __restrict__ glabels, float* __restrict__ partial)
{
    const int b = blockIdx.x;
    const int tid = threadIdx.x;

    __shared__ float lz[HWA];                 // 42588 B
    __shared__ int   hist1[256];
    __shared__ int   hist2[256];
    __shared__ float cand[CAP];
    __shared__ int   s_idx[NGT];
    __shared__ float s_row[NGT][13];
    __shared__ int   s_cand[3 * NGT];
    __shared__ int   s_conf[3 * NGT];
    __shared__ int   s_src[3 * NGT];
    __shared__ int   s_ncand, s_npos, s_k, s_e, s_m, s_r, s_ccount;
    __shared__ float s_extra;
    __shared__ unsigned long long kred[16];
    __shared__ float fred[16];

    // ---- Phase A: per-GT matching (threads 0..7) + zero histograms ----
    if (tid < 256) { hist1[tid] = 0; hist2[tid] = 0; }
    if (tid < NGT) {
        const int i = tid;
        const float* gb = gboxes + ((size_t)b * NGT + i) * 4;
        const float l = gb[0], t = gb[1], r = gb[2], bo = gb[3];
        const float cx = (l + r) * 0.5f, cy = (t + bo) * 0.5f;
        const float w = r - l, h = bo - t;
        const float area_g = w * h;
        const float AW[9] = {0.0276f, 0.0386f, 0.0795f, 0.0721f, 0.1495f, 0.1421f, 0.2788f, 0.375f, 0.897f};
        const float AH[9] = {0.0361f, 0.0697f, 0.0553f, 0.1466f, 0.1087f, 0.2861f, 0.2163f, 0.476f, 0.784f};
        float best = -1.f, baw = AW[0], bah = AH[0];
        int id = 0;
#pragma unroll
        for (int a = 0; a < 9; ++a) {
            float inter = fminf(w, AW[a]) * fminf(h, AH[a]);
            float iou = inter / (area_g + AW[a] * AH[a] - inter);
            if (iou > best) { best = iou; id = a; baw = AW[a]; bah = AH[a]; }
        }
        const int ceng = id / 3, anc = id % 3;
        const int grid = (ceng == 0) ? 52 : ((ceng == 1) ? 26 : 13);
        const int coff = (ceng == 0) ? 0 : ((ceng == 1) ? 8112 : 10140);
        const float gf = (float)grid;
        const int col = (int)(cx * gf);
        const int row = (int)(cy * gf);
        s_idx[i] = coff + (row * grid + col) * 3 + anc;
        float* rr = s_row[i];
        const int lab = glabels[b * NGT + i] - 1;
        rr[0] = 1.f;
        rr[1] = (lab == 0) ? 1.f : 0.f;
        rr[2] = (lab == 1) ? 1.f : 0.f;
        rr[3] = (lab == 2) ? 1.f : 0.f;
        rr[4] = (cx - (float)col / gf) * gf;
        rr[5] = (cy - (float)row / gf) * gf;
        rr[6] = logf(w / baw);
        rr[7] = logf(h / bah);
        rr[8] = 2.f - area_g;
        rr[9] = l; rr[10] = t; rr[11] = r; rr[12] = bo;
    }
    __syncthreads();

    // ---- Phase B: lz (g=0 BCE) into LDS + exponent-byte histogram ----
    const float* pc = pconf + (size_t)b * HWA;
    for (int p = tid; p < HWA; p += NTH) {
        const float ps = sigmoid_clip(pc[p]);
        const float v = -log1pf(-ps);
        lz[p] = v;
        atomicAdd(&hist1[__float_as_uint(v) >> 23], 1);
    }
    __syncthreads();

    // ---- Phase A2 (thread 0): scatter replay, masking, k, L1 scan ----
    if (tid == 0) {
        int ncand = 0;
        for (int i = 0; i < NGT; ++i)
            for (int d = 0; d < 3; ++d) {
                int p = s_idx[i] + d;
                if (p >= HWA) continue;              // OOB scatter dropped
                bool seen = false;
                for (int j = 0; j < ncand; ++j) if (s_cand[j] == p) { seen = true; break; }
                if (!seen) s_cand[ncand++] = p;
            }
        int npos = 0;
        for (int c = 0; c < ncand; ++c) {
            const int p = s_cand[c];
            int conf = 0, src = -1;
            for (int i = 0; i < NGT; ++i) {
                const int di = p - s_idx[i];
                if (di >= 0 && di < 3) conf = -1;     // ignore-mark col 0
                if (di == 0) { conf = 1; src = i; }   // full-row set
            }
            s_conf[c] = conf; s_src[c] = src;
            if (conf == 1) npos++;
            // mask lz (pos|ign -> 0) and fix the histogram
            const float old = lz[p];
            hist1[__float_as_uint(old) >> 23]--;
            hist1[0]++;
            lz[p] = 0.f;
        }
        s_ncand = ncand; s_npos = npos;
        const float nums_pos = fmaxf((float)npos, FP16_EPS);
        const int k = (int)ceilf(nums_pos * 3.f);
        s_k = k;
        // L1: find exponent bin of the kth largest
        int cum = 0;
        for (int e = 255; e >= 0; --e) {
            const int h = hist1[e];
            if (cum + h >= k) { s_e = e; s_r = cum; break; }  // s_r reused: cntAbove(L1)
            cum += h;
        }
        s_extra = 0.f;
    }
    __syncthreads();

    // ---- Pass 2: sum values above exponent bin; histogram mantissa-high within bin ----
    const int k = s_k;
    const int eStar = s_e;
    float psum = 0.f;
    for (int p = tid; p < HWA; p += NTH) {
        const float v = lz[p];
        const unsigned u = __float_as_uint(v);
        const int ex = (int)(u >> 23);
        if (ex > eStar) psum += v;
        else if (ex == eStar) atomicAdd(&hist2[(u >> 15) & 0xff], 1);
    }
    __syncthreads();

    if (tid == 0) {
        int cum = s_r;   // count strictly above exponent bin
        for (int m = 255; m >= 0; --m) {
            const int h = hist2[m];
            if (cum + h >= k) { s_m = m; s_r = k - cum; break; }
            cum += h;
        }
        s_ccount = 0;
    }
    __syncthreads();

    // ---- Pass 3: sum above 16-bit boundary key; gather boundary candidates ----
    const int mStar = s_m;
    for (int p = tid; p < HWA; p += NTH) {
        const float v = lz[p];
        const unsigned u = __float_as_uint(v);
        if ((int)(u >> 23) == eStar) {
            const int mb = (int)((u >> 15) & 0xff);
            if (mb > mStar) psum += v;
            else if (mb == mStar) {
                const int c = atomicAdd(&s_ccount, 1);
                if (c < CAP) cand[c] = v;
            }
        }
    }
    __syncthreads();

    // deterministic block reduce of psum
    {
        float v = psum;
#pragma unroll
        for (int off = 32; off > 0; off >>= 1) v += __shfl_down(v, off, 64);
        if ((tid & 63) == 0) fred[tid >> 6] = v;
    }
    __syncthreads();

    // ---- exact top-r among boundary candidates (r typically 1-3, <=24) ----
    const int r = s_r;
    const int ccount = min(s_ccount, CAP);
    for (int it = 0; it < r; ++it) {
        float bv = 0.f; int bi = -1;
        for (int c = tid; c < ccount; c += NTH) {
            const float v = cand[c];
            if (v >= 0.f && (bi < 0 || v > bv)) { bv = v; bi = c; }
        }
        unsigned long long key = (bi >= 0)
            ? (((unsigned long long)(__float_as_uint(bv) + 1u) << 32) | (unsigned)bi)
            : 0ull;
#pragma unroll
        for (int off = 32; off > 0; off >>= 1) {
            unsigned long long o = __shfl_down(key, off, 64);
            if (o > key) key = o;
        }
        if ((tid & 63) == 0) kred[tid >> 6] = key;
        __syncthreads();
        if (tid == 0) {
            unsigned long long kk = kred[0];
            for (int wv = 1; wv < 16; ++wv) if (kred[wv] > kk) kk = kred[wv];
            const int idx = (int)(kk & 0xffffffffu);
            s_extra += cand[idx];
            cand[idx] = -1.f;
        }
        __syncthreads();
    }

    // ---- Phase D: positive-position terms + final (thread 0) ----
    if (tid == 0) {
        float negsum = s_extra;
        for (int wv = 0; wv < 16; ++wv) negsum += fred[wv];
        float l_cls = 0.f, l_conf_pos = 0.f, l_txty = 0.f, l_twth = 0.f;
        for (int c = 0; c < s_ncand; ++c) {
            if (s_conf[c] != 1) continue;
            const int p = s_cand[c];
            const float* rr = s_row[s_src[c]];
            l_conf_pos += -logf(sigmoid_clip(pc[p]));
            const float* pcl = pcls + ((size_t)b * HWA + p) * 3;
#pragma unroll
            for (int cc = 0; cc < 3; ++cc) {
                const float sc = sigmoid_clip(pcl[cc]);
                const float g = rr[1 + cc];
                l_cls += -(g * logf(sc) + (1.f - g) * log1pf(-sc));
            }
            const float* pt = ptxywh + ((size_t)b * HWA + p) * 4;
            const float wgt = rr[8];
            float acc = 0.f;
#pragma unroll
            for (int cc = 0; cc < 2; ++cc) {
                const float st = sigmoid_clip(pt[cc]);
                const float g = rr[4 + cc];
                acc += -(g * logf(st) + (1.f - g) * log1pf(-st));
            }
            l_txty += acc * wgt;
            const float d0 = pt[2] - rr[6], d1 = pt[3] - rr[7];
            l_twth += (d0 * d0 + d1 * d1) * wgt;
        }
        const float nums_pos = fmaxf((float)s_npos, FP16_EPS);
        partial[b] = (l_conf_pos + negsum + l_cls + l_txty + l_twth) / nums_pos;
    }
}

__global__ __launch_bounds__(256) void yolo_loss_reduce(
    const float* __restrict__ partial, float* __restrict__ out)
{
    const int tid = threadIdx.x;
    float v = partial[tid];
#pragma unroll
    for (int off = 32; off > 0; off >>= 1) v += __shfl_down(v, off, 64);
    __shared__ float s[4];
    if ((tid & 63) == 0) s[tid >> 6] = v;
    __syncthreads();
    if (tid == 0) out[0] = (s[0] + s[1] + s[2] + s[3]) * (1.f / (float)BB);
}

extern "C" void kernel_launch(void* const* d_in, const int* in_sizes, int n_in,
                              void* d_out, int out_size, void* d_ws, size_t ws_size,
                              hipStream_t stream) {
    const float* pconf  = (const float*)d_in[0];
    const float* pcls   = (const float*)d_in[1];
    const float* ptxywh = (const float*)d_in[2];
    const float* gboxes = (const float*)d_in[3];
    const int*   glabels = (const int*)d_in[4];
    float* out = (float*)d_out;
    float* partial = (float*)d_ws;

    yolo_loss_batch<<<BB, NTH, 0, stream>>>(pconf, pcls, ptxywh, gboxes, glabels, partial);
    yolo_loss_reduce<<<1, 256, 0, stream>>>(partial, out);
}

// Round 3
// 34.699 us; speedup vs baseline: 3.4619x; 2.4406x over previous
//
#include <hip/hip_runtime.h>
#include <hip/hip_bf16.h>

#define BB 256
#define NGT 8
#define HWA 10647
#define NTH 1024
#define CAP 6144
#define EPSF 1e-6f
#define FP16_EPS 0.0009765625f

__device__ __forceinline__ float sigmoid_clip(float x) {
    float s = 1.f / (1.f + expf(-x));
    return fminf(fmaxf(s, EPSF), 1.f - EPSF);
}

__global__ __launch_bounds__(NTH) void yolo_loss_batch(
    const float* __restrict__ pconf, const float* __restrict__ pcls,
    const float* __restrict__ ptxywh, const float* __restrict__ gboxes,
    const int* __restrict__ glabels, float* __restrict__ partial)
{
    const int b = blockIdx.x;
    const int tid = threadIdx.x;
    const int lane = tid & 63;

    __shared__ float lz[HWA];                 // 42588 B
    __shared__ int   hist[256];
    __shared__ int   hist2[256];
    __shared__ float cand[CAP];
    __shared__ int   s_idx[NGT];
    __shared__ float s_row[NGT][13];
    __shared__ int   s_npos, s_ccount, s_e, s_above, s_m;
    __shared__ int   wtot[4];
    __shared__ float fred[16];

    // ---- init + issue phase-A loads early ----
    float gl = 0.f, gt = 0.f, gr = 0.f, gbo = 0.f;
    int lab = 0;
    if (tid < NGT) {
        const float* gb = gboxes + ((size_t)b * NGT + tid) * 4;
        gl = gb[0]; gt = gb[1]; gr = gb[2]; gbo = gb[3];
        lab = glabels[b * NGT + tid] - 1;
    }
    if (tid < 256) { hist[tid] = 0; hist2[tid] = 0; }
    if (tid == 0)  { s_npos = 0; s_ccount = 0; }
    __syncthreads();   // B0: hists zeroed before any atomics

    // ---- Phase A: per-GT matching (threads 0..7) ----
    if (tid < NGT) {
        const float cx = (gl + gr) * 0.5f, cy = (gt + gbo) * 0.5f;
        const float w = gr - gl, h = gbo - gt;
        const float area_g = w * h;
        const float AW[9] = {0.0276f, 0.0386f, 0.0795f, 0.0721f, 0.1495f, 0.1421f, 0.2788f, 0.375f, 0.897f};
        const float AH[9] = {0.0361f, 0.0697f, 0.0553f, 0.1466f, 0.1087f, 0.2861f, 0.2163f, 0.476f, 0.784f};
        float best = -1.f, baw = AW[0], bah = AH[0];
        int id = 0;
#pragma unroll
        for (int a = 0; a < 9; ++a) {
            float inter = fminf(w, AW[a]) * fminf(h, AH[a]);
            float iou = inter / (area_g + AW[a] * AH[a] - inter);
            if (iou > best) { best = iou; id = a; baw = AW[a]; bah = AH[a]; }
        }
        const int ceng = id / 3, anc = id % 3;
        const int grid = (ceng == 0) ? 52 : ((ceng == 1) ? 26 : 13);
        const int coff = (ceng == 0) ? 0 : ((ceng == 1) ? 8112 : 10140);
        const float gf = (float)grid;
        const int col = (int)(cx * gf);
        const int row = (int)(cy * gf);
        s_idx[tid] = coff + (row * grid + col) * 3 + anc;
        float* rr = s_row[tid];
        rr[0] = 1.f;
        rr[1] = (lab == 0) ? 1.f : 0.f;
        rr[2] = (lab == 1) ? 1.f : 0.f;
        rr[3] = (lab == 2) ? 1.f : 0.f;
        rr[4] = (cx - (float)col / gf) * gf;
        rr[5] = (cy - (float)row / gf) * gf;
        rr[6] = logf(w / baw);
        rr[7] = logf(h / bah);
        rr[8] = 2.f - area_g;
        rr[9] = gl; rr[10] = gt; rr[11] = gr; rr[12] = gbo;
    }

    // ---- Phase B: lz + exponent histogram ----
    const float* pc = pconf + (size_t)b * HWA;
    float psum = 0.f;     // single accumulator for ALL loss terms of this block
    for (int p = tid; p < HWA; p += NTH) {
        const float ps = sigmoid_clip(pc[p]);
        const float v = -log1pf(-ps);
        lz[p] = v;
        atomicAdd(&hist[__float_as_uint(v) >> 23], 1);
    }
    __syncthreads();   // B1: lz, hist, s_idx/s_row ready

    // ---- Phase A2: parallel scatter replay (threads 0..23) ----
    int myconf = 0, mysrc = -1, myp = -1; bool canon = false;
    if (tid < 3 * NGT) {
        const int i = tid / 3, d = tid % 3;
        const int p = s_idx[i] + d;
        if (p < HWA) {               // OOB scatter dropped by JAX
            myp = p;
            canon = true;
            for (int c2 = 0; c2 < tid; ++c2) {
                if (s_idx[c2 / 3] + (c2 % 3) == p) { canon = false; break; }
            }
#pragma unroll
            for (int j = 0; j < NGT; ++j) {
                const int dj = p - s_idx[j];
                if (dj >= 0 && dj < 3) myconf = -1;     // ignore-mark col0
                if (dj == 0) { myconf = 1; mysrc = j; } // full-row set
            }
            if (canon) {
                const float old = lz[p];
                atomicAdd(&hist[__float_as_uint(old) >> 23], -1);
                atomicAdd(&hist[0], 1);
                lz[p] = 0.f;
                if (myconf == 1) atomicAdd(&s_npos, 1);
            }
        }
    }
    __syncthreads();   // B2: npos final, hist fixed, lz masked

    const int npos = s_npos;
    const float nums_pos = fmaxf((float)npos, FP16_EPS);
    const int k = (npos > 0) ? (3 * npos) : 1;

    // ---- boundary-exponent search: parallel suffix scan over hist ----
    int hv = 0, sfx = 0;
    if (tid < 256) {
        hv = hist[tid];
        sfx = hv;
#pragma unroll
        for (int off = 1; off < 64; off <<= 1) {
            const int o = __shfl_down(sfx, off, 64);
            sfx += (lane + off < 64) ? o : 0;
        }
        if (lane == 0) wtot[tid >> 6] = sfx;
    }
    __syncthreads();   // B3
    if (tid < 256) {
        const int w = tid >> 6;
        for (int w2 = w + 1; w2 < 4; ++w2) sfx += wtot[w2];
        const int above = sfx - hv;
        if (above < k && above + hv >= k) { s_e = tid; s_above = above; }
    }
    __syncthreads();   // B4: s_e, s_above known

    const int eStar = s_e;
    const bool fits = (hist[eStar] <= CAP);

    // ---- Phase D: positive-position terms (canonical positive lanes) ----
    if (canon && myconf == 1) {
        const float* rr = s_row[mysrc];
        const int p = myp;
        float acc = -logf(sigmoid_clip(pc[p]));
        const float* pcl = pcls + ((size_t)b * HWA + p) * 3;
#pragma unroll
        for (int cc = 0; cc < 3; ++cc) {
            const float sc = sigmoid_clip(pcl[cc]);
            const float g = rr[1 + cc];
            acc += -(g * logf(sc) + (1.f - g) * log1pf(-sc));
        }
        const float* pt = ptxywh + ((size_t)b * HWA + p) * 4;
        const float wgt = rr[8];
        float a2 = 0.f;
#pragma unroll
        for (int cc = 0; cc < 2; ++cc) {
            const float st = sigmoid_clip(pt[cc]);
            const float g = rr[4 + cc];
            a2 += -(g * logf(st) + (1.f - g) * log1pf(-st));
        }
        acc += a2 * wgt;
        const float d0 = pt[2] - rr[6], d1 = pt[3] - rr[7];
        acc += (d0 * d0 + d1 * d1) * wgt;
        psum += acc;
    }

    // ---- Pass 2: sum above bin, gather boundary bin ----
    for (int p = tid; p < HWA; p += NTH) {
        const float v = lz[p];
        const unsigned u = __float_as_uint(v);
        const int ex = (int)(u >> 23);
        if (ex > eStar) psum += v;
        else if (ex == eStar) {
            if (fits) { const int c = atomicAdd(&s_ccount, 1); cand[c] = v; }
            else atomicAdd(&hist2[(u >> 15) & 0xff], 1);
        }
    }
    __syncthreads();   // B5: cand (or hist2) ready

    int rneed;
    if (fits) {
        rneed = k - s_above;
    } else {
        // rare fallback: refine by next 8 mantissa bits
        int hv2 = 0, sfx2 = 0;
        if (tid < 256) {
            hv2 = hist2[tid];
            sfx2 = hv2;
#pragma unroll
            for (int off = 1; off < 64; off <<= 1) {
                const int o = __shfl_down(sfx2, off, 64);
                sfx2 += (lane + off < 64) ? o : 0;
            }
            if (lane == 0) wtot[tid >> 6] = sfx2;
        }
        __syncthreads();
        if (tid < 256) {
            const int w = tid >> 6;
            for (int w2 = w + 1; w2 < 4; ++w2) sfx2 += wtot[w2];
            const int above2 = s_above + (sfx2 - hv2);
            if (above2 < k && above2 + hv2 >= k) { s_m = tid; }
        }
        __syncthreads();
        const int mStar = s_m;
        int add_above = 0;
        for (int p = tid; p < HWA; p += NTH) {
            const float v = lz[p];
            const unsigned u = __float_as_uint(v);
            if ((int)(u >> 23) == eStar) {
                const int mb = (int)((u >> 15) & 0xff);
                if (mb > mStar) { psum += v; }
                else if (mb == mStar) {
                    const int c = atomicAdd(&s_ccount, 1);
                    if (c < CAP) cand[c] = v;
                }
            }
        }
        // recompute count above the 16-bit key for rneed (thread-uniform via scan values)
        if (tid < 256 && tid == s_m) { s_above = s_above + (sfx2 - hv2); }
        __syncthreads();
        rneed = k - s_above;
        (void)add_above;
    }

    // ---- one-shot rank select over candidate array ----
    const int C = min(s_ccount, CAP);
    for (int t = tid; t < C; t += NTH) {
        const float v = cand[t];
        int rank = 0;
        for (int j = 0; j < C; ++j) {
            const float w = cand[j];
            rank += (w > v) || (w == v && j < t);
        }
        if (rank < rneed) psum += v;
    }

    // ---- deterministic block reduction ----
    {
        float v = psum;
#pragma unroll
        for (int off = 32; off > 0; off >>= 1) v += __shfl_down(v, off, 64);
        if (lane == 0) fred[tid >> 6] = v;
    }
    __syncthreads();
    if (tid == 0) {
        float t = 0.f;
#pragma unroll
        for (int w = 0; w < 16; ++w) t += fred[w];
        partial[b] = t / nums_pos;
    }
}

__global__ __launch_bounds__(256) void yolo_loss_reduce(
    const float* __restrict__ partial, float* __restrict__ out)
{
    const int tid = threadIdx.x;
    float v = partial[tid];
#pragma unroll
    for (int off = 32; off > 0; off >>= 1) v += __shfl_down(v, off, 64);
    __shared__ float s[4];
    if ((tid & 63) == 0) s[tid >> 6] = v;
    __syncthreads();
    if (tid == 0) out[0] = (s[0] + s[1] + s[2] + s[3]) * (1.f / (float)BB);
}

extern "C" void kernel_launch(void* const* d_in, const int* in_sizes, int n_in,
                              void* d_out, int out_size, void* d_ws, size_t ws_size,
                              hipStream_t stream) {
    const float* pconf   = (const float*)d_in[0];
    const float* pcls    = (const float*)d_in[1];
    const float* ptxywh  = (const float*)d_in[2];
    const float* gboxes  = (const float*)d_in[3];
    const int*   glabels = (const int*)d_in[4];
    float* out = (float*)d_out;
    float* partial = (float*)d_ws;

    yolo_loss_batch<<<BB, NTH, 0, stream>>>(pconf, pcls, ptxywh, gboxes, glabels, partial);
    yolo_loss_reduce<<<1, 256, 0, stream>>>(partial, out);
}

// Round 4
// 25.886 us; speedup vs baseline: 4.6405x; 1.3405x over previous
//
#include <hip/hip_runtime.h>
#include <hip/hip_bf16.h>

#define BB 256
#define NGT 8
#define HWA 10647
#define NTH 1024
#define NREG 11          // ceil(HWA/NTH)
#define CAP 1024
#define NAB 96           // above-boundary count < k <= 72
#define EPSF 1e-6f
#define FP16_EPS 0.0009765625f

// exact reference value: -log1p(-clip(sigmoid(x)))
__device__ __forceinline__ float lv_exact(float x) {
    float s = 1.f / (1.f + expf(-x));
    s = fminf(fmaxf(s, EPSF), 1.f - EPSF);
    return -log1pf(-s);
}
// order-monotone unsigned key for float compare
__device__ __forceinline__ unsigned fkey(float x) {
    const unsigned u = __float_as_uint(x);
    return u ^ ((u & 0x80000000u) ? 0xFFFFFFFFu : 0x80000000u);
}

__global__ __launch_bounds__(NTH) void yolo_loss_batch(
    const float* __restrict__ pconf, const float* __restrict__ pcls,
    const float* __restrict__ ptxywh, const float* __restrict__ gboxes,
    const int* __restrict__ glabels, float* __restrict__ partial)
{
    const int b = blockIdx.x;
    const int tid = threadIdx.x;
    const int lane = tid & 63;

    __shared__ int   hist[256];
    __shared__ int   hist2[256];
    __shared__ float cand[CAP];
    __shared__ float sab[NAB];
    __shared__ int   s_idx[NGT];
    __shared__ float s_row[NGT][13];
    __shared__ int   s_npos, s_ccount, s_nab, s_b, s_above, s_m;
    __shared__ int   wtot[4];
    __shared__ float fred[16];

    // ---- issue all global loads early ----
    float gl = 0.f, gt = 0.f, gr = 0.f, gbo = 0.f;
    int lab = 0;
    if (tid < NGT) {
        const float* gb = gboxes + ((size_t)b * NGT + tid) * 4;
        gl = gb[0]; gt = gb[1]; gr = gb[2]; gbo = gb[3];
        lab = glabels[b * NGT + tid] - 1;
    }
    const float* pc = pconf + (size_t)b * HWA;
    float x[NREG];
#pragma unroll
    for (int v = 0; v < NREG; ++v) {
        const int p = tid + v * NTH;
        x[v] = (p < HWA) ? pc[p] : 0.f;
    }
    if (tid < 256) { hist[tid] = 0; hist2[tid] = 0; }
    if (tid == 0)  { s_npos = 0; s_ccount = 0; s_nab = 0; }

    // ---- Phase A: per-GT matching (threads 0..7) ----
    if (tid < NGT) {
        const float cx = (gl + gr) * 0.5f, cy = (gt + gbo) * 0.5f;
        const float w = gr - gl, h = gbo - gt;
        const float area_g = w * h;
        const float AW[9] = {0.0276f, 0.0386f, 0.0795f, 0.0721f, 0.1495f, 0.1421f, 0.2788f, 0.375f, 0.897f};
        const float AH[9] = {0.0361f, 0.0697f, 0.0553f, 0.1466f, 0.1087f, 0.2861f, 0.2163f, 0.476f, 0.784f};
        float best = -1.f, baw = AW[0], bah = AH[0];
        int id = 0;
#pragma unroll
        for (int a = 0; a < 9; ++a) {
            float inter = fminf(w, AW[a]) * fminf(h, AH[a]);
            float iou = inter / (area_g + AW[a] * AH[a] - inter);
            if (iou > best) { best = iou; id = a; baw = AW[a]; bah = AH[a]; }
        }
        const int ceng = id / 3, anc = id % 3;
        const int grid = (ceng == 0) ? 52 : ((ceng == 1) ? 26 : 13);
        const int coff = (ceng == 0) ? 0 : ((ceng == 1) ? 8112 : 10140);
        const float gf = (float)grid;
        const int col = (int)(cx * gf);
        const int row = (int)(cy * gf);
        s_idx[tid] = coff + (row * grid + col) * 3 + anc;
        float* rr = s_row[tid];
        rr[0] = 1.f;
        rr[1] = (lab == 0) ? 1.f : 0.f;
        rr[2] = (lab == 1) ? 1.f : 0.f;
        rr[3] = (lab == 2) ? 1.f : 0.f;
        rr[4] = (cx - (float)col / gf) * gf;
        rr[5] = (cy - (float)row / gf) * gf;
        rr[6] = logf(w / baw);
        rr[7] = logf(h / bah);
        rr[8] = 2.f - area_g;
        rr[9] = gl; rr[10] = gt; rr[11] = gr; rr[12] = gbo;
    }
    __syncthreads();   // B1: s_idx/s_row ready, hists zeroed

    // hoist match indices to registers (broadcast LDS reads)
    int idxr[NGT];
#pragma unroll
    for (int j = 0; j < NGT; ++j) idxr[j] = s_idx[j];

    float psum = 0.f;  // this thread's share of every loss term

    // ---- Phase A2: scatter replay on threads 0..23 (depends only on s_idx) ----
    int myconf = 0, mysrc = -1, myp = -1; bool canon = false;
    if (tid < 3 * NGT) {
        const int i = tid / 3, d = tid % 3;
        const int p = idxr[i] + d;
        if (p < HWA) {                    // OOB scatter dropped by JAX
            myp = p;
            canon = true;
            for (int c2 = 0; c2 < tid; ++c2)
                if (idxr[c2 / 3] + (c2 % 3) == p) { canon = false; break; }
#pragma unroll
            for (int j = 0; j < NGT; ++j) {
                const int dj = p - idxr[j];
                if (dj >= 0 && dj < 3) myconf = -1;     // ignore-mark col0
                if (dj == 0) { myconf = 1; mysrc = j; } // full-row set
            }
            if (canon && myconf == 1) atomicAdd(&s_npos, 1);
        }
    }

    // ---- Phase D: positive-position terms (≤24 lanes; independent of hist) ----
    if (canon && myconf == 1) {
        const float* rr = s_row[mysrc];
        const int p = myp;
        float acc = -logf(fminf(fmaxf(1.f / (1.f + expf(-pc[p])), EPSF), 1.f - EPSF));
        const float* pcl = pcls + ((size_t)b * HWA + p) * 3;
#pragma unroll
        for (int cc = 0; cc < 3; ++cc) {
            const float sc = fminf(fmaxf(1.f / (1.f + expf(-pcl[cc])), EPSF), 1.f - EPSF);
            const float g = rr[1 + cc];
            acc += -(g * logf(sc) + (1.f - g) * log1pf(-sc));
        }
        const float* pt = ptxywh + ((size_t)b * HWA + p) * 4;
        const float wgt = rr[8];
        float a2 = 0.f;
#pragma unroll
        for (int cc = 0; cc < 2; ++cc) {
            const float st = fminf(fmaxf(1.f / (1.f + expf(-pt[cc])), EPSF), 1.f - EPSF);
            const float g = rr[4 + cc];
            a2 += -(g * logf(st) + (1.f - g) * log1pf(-st));
        }
        acc += a2 * wgt;
        const float d0 = pt[2] - rr[6], d1 = pt[3] - rr[7];
        acc += (d0 * d0 + d1 * d1) * wgt;
        psum += acc;
    }

    // ---- Phase B: mask + key histogram on raw x (no libm) ----
    unsigned mmask = 0;
#pragma unroll
    for (int v = 0; v < NREG; ++v) {
        const int p = tid + v * NTH;
        if (p < HWA) {
            bool m = false;
#pragma unroll
            for (int j = 0; j < NGT; ++j) {
                const int dj = p - idxr[j];
                m = m || (dj >= 0 && dj < 3);
            }
            if (m) mmask |= (1u << v);
            else atomicAdd(&hist[fkey(x[v]) >> 24], 1);
        } else mmask |= (1u << v);
    }
    __syncthreads();   // B2: hist + npos final

    const int npos = s_npos;
    const float nums_pos = fmaxf((float)npos, FP16_EPS);
    const int k = (npos > 0) ? (3 * npos) : 1;

    // ---- boundary-byte search: parallel suffix scan over hist ----
    int hv = 0, sfx = 0;
    if (tid < 256) {
        hv = hist[tid];
        sfx = hv;
#pragma unroll
        for (int off = 1; off < 64; off <<= 1) {
            const int o = __shfl_down(sfx, off, 64);
            sfx += (lane + off < 64) ? o : 0;
        }
        if (lane == 0) wtot[tid >> 6] = sfx;
    }
    __syncthreads();   // B3
    if (tid < 256) {
        const int w = tid >> 6;
        for (int w2 = w + 1; w2 < 4; ++w2) sfx += wtot[w2];
        const int above = sfx - hv;
        if (above < k && above + hv >= k) { s_b = tid; s_above = above; }
    }
    __syncthreads();   // B4: s_b, s_above known

    const int bStar = s_b;
    const bool fits = (hist[bStar] <= CAP);

    // ---- gather above-boundary + boundary-bin from registers ----
#pragma unroll
    for (int v = 0; v < NREG; ++v) {
        if (!(mmask & (1u << v))) {
            const unsigned kb = fkey(x[v]) >> 24;
            if ((int)kb > bStar) {
                const int i = atomicAdd(&s_nab, 1);
                sab[i] = x[v];
            } else if ((int)kb == bStar) {
                if (fits) { const int c = atomicAdd(&s_ccount, 1); cand[c] = x[v]; }
                else atomicAdd(&hist2[(fkey(x[v]) >> 16) & 0xff], 1);
            }
        }
    }
    __syncthreads();   // B5: sab/cand (or hist2) ready

    // compacted libm for above-boundary values (≤72 → ~1 wave-pass)
    for (int t = tid; t < s_nab; t += NTH) psum += lv_exact(sab[t]);

    int rneed;
    if (fits) {
        rneed = k - s_above;
    } else {
        // rare fallback: refine by next 8 key bits
        int hv2 = 0, sfx2 = 0;
        if (tid < 256) {
            hv2 = hist2[tid];
            sfx2 = hv2;
#pragma unroll
            for (int off = 1; off < 64; off <<= 1) {
                const int o = __shfl_down(sfx2, off, 64);
                sfx2 += (lane + off < 64) ? o : 0;
            }
            if (lane == 0) wtot[tid >> 6] = sfx2;
        }
        __syncthreads();
        if (tid < 256) {
            const int w = tid >> 6;
            for (int w2 = w + 1; w2 < 4; ++w2) sfx2 += wtot[w2];
            const int above2 = s_above + (sfx2 - hv2);
            if (above2 < k && above2 + hv2 >= k) { s_m = tid; s_above = above2; }
        }
        __syncthreads();
        const int mStar = s_m;
#pragma unroll
        for (int v = 0; v < NREG; ++v) {
            if (!(mmask & (1u << v))) {
                const unsigned kk = fkey(x[v]);
                if ((int)(kk >> 24) == bStar) {
                    const int mb = (int)((kk >> 16) & 0xff);
                    if (mb > mStar) psum += lv_exact(x[v]);
                    else if (mb == mStar) {
                        const int c = atomicAdd(&s_ccount, 1);
                        if (c < CAP) cand[c] = x[v];
                    }
                }
            }
        }
        __syncthreads();
        rneed = k - s_above;
    }

    // ---- one-shot rank select over boundary candidates (compare raw x) ----
    const int C = min(s_ccount, CAP);
    for (int t = tid; t < C; t += NTH) {
        const float v = cand[t];
        int rank = 0;
        for (int j = 0; j < C; ++j) {
            const float w = cand[j];
            rank += (w > v) || (w == v && j < t);
        }
        if (rank < rneed) psum += lv_exact(v);
    }

    // ---- deterministic block reduction ----
    {
        float v = psum;
#pragma unroll
        for (int off = 32; off > 0; off >>= 1) v += __shfl_down(v, off, 64);
        if (lane == 0) fred[tid >> 6] = v;
    }
    __syncthreads();
    if (tid == 0) {
        float t = 0.f;
#pragma unroll
        for (int w = 0; w < 16; ++w) t += fred[w];
        partial[b] = t / nums_pos;
    }
}

__global__ __launch_bounds__(256) void yolo_loss_reduce(
    const float* __restrict__ partial, float* __restrict__ out)
{
    const int tid = threadIdx.x;
    float v = partial[tid];
#pragma unroll
    for (int off = 32; off > 0; off >>= 1) v += __shfl_down(v, off, 64);
    __shared__ float s[4];
    if ((tid & 63) == 0) s[tid >> 6] = v;
    __syncthreads();
    if (tid == 0) out[0] = (s[0] + s[1] + s[2] + s[3]) * (1.f / (float)BB);
}

extern "C" void kernel_launch(void* const* d_in, const int* in_sizes, int n_in,
                              void* d_out, int out_size, void* d_ws, size_t ws_size,
                              hipStream_t stream) {
    const float* pconf   = (const float*)d_in[0];
    const float* pcls    = (const float*)d_in[1];
    const float* ptxywh  = (const float*)d_in[2];
    const float* gboxes  = (const float*)d_in[3];
    const int*   glabels = (const int*)d_in[4];
    float* out = (float*)d_out;
    float* partial = (float*)d_ws;

    yolo_loss_batch<<<BB, NTH, 0, stream>>>(pconf, pcls, ptxywh, gboxes, glabels, partial);
    yolo_loss_reduce<<<1, 256, 0, stream>>>(partial, out);
}